// Round 11
// baseline (10487.115 us; speedup 1.0000x reference)
//
#include <hip/hip_runtime.h>
#include <math.h>

typedef short short8 __attribute__((ext_vector_type(8)));
typedef float f32x4 __attribute__((ext_vector_type(4)));
typedef unsigned long long u64;
typedef u64 u64x2 __attribute__((ext_vector_type(2)));

#define DT 0.042f
#define LSEQ 512
#define NI 96
#define NH 1024

static __device__ __forceinline__ unsigned short f2bf(float f) {
  unsigned int u = __builtin_bit_cast(unsigned int, f);
  return (unsigned short)((u + 0x7fffu + ((u >> 16) & 1u)) >> 16);
}
static __device__ __forceinline__ float bf2f(unsigned short h) {
  unsigned int u = ((unsigned int)h) << 16;
  return __builtin_bit_cast(float, u);
}
static __device__ __forceinline__ float fast_tanhf(float a) {
  float ax = __builtin_fabsf(a);
  float e = __expf(2.0f * ax);  // overflow -> inf -> t = 1, no NaN
  float t = 1.0f - 2.0f / (e + 1.0f);
  return a < 0.0f ? -t : t;
}

// F=true (verified co-XCD group): data via sc0 (XCD L2, r8-proven); flag POSTS via
// sc0 store; flag POLLS via workgroup-scope atomic fetch_add(0) — atomics execute at
// the L2 endpoint and never read L1 (kills r9's L1-sticky poll staleness) and never
// leave the XCD (kills r8/r10's IC round trip).
// F=false: relaxed agent atomics via IC everywhere (proven r2/3/5/8/10).
template <bool F>
static __device__ __forceinline__ void ld16_issue(u64x2* dst, const u64* p) {
  if constexpr (F) {
    asm volatile("global_load_dwordx4 %0, %1, off sc0" : "=v"(*dst) : "v"(p) : "memory");
  } else {
    u64 a = __hip_atomic_load(p, __ATOMIC_RELAXED, __HIP_MEMORY_SCOPE_AGENT);
    u64 b = __hip_atomic_load(p + 1, __ATOMIC_RELAXED, __HIP_MEMORY_SCOPE_AGENT);
    *dst = (u64x2){a, b};
  }
}
template <bool F>
static __device__ __forceinline__ void stpub(unsigned int* p, unsigned int v) {
  if constexpr (F)
    asm volatile("global_store_dword %0, %1, off sc0" ::"v"(p), "v"(v) : "memory");
  else
    __hip_atomic_store(p, v, __ATOMIC_RELAXED, __HIP_MEMORY_SCOPE_AGENT);
}
template <bool F>
static __device__ __forceinline__ void stflag(unsigned int* p, unsigned int v) {
  if constexpr (F)
    asm volatile("global_store_dword %0, %1, off sc0" ::"v"(p), "v"(v) : "memory");
  else
    __hip_atomic_store(p, v, __ATOMIC_RELAXED, __HIP_MEMORY_SCOPE_AGENT);
}
static __device__ __forceinline__ void st_out(float* p, float v) {
  asm volatile("global_store_dword %0, %1, off" ::"v"(p), "v"(v) : "memory");
}
static __device__ __forceinline__ void drain_vm() {  // wave-local full drain
  asm volatile("s_waitcnt vmcnt(0)" ::: "memory");
  __builtin_amdgcn_sched_barrier(0);
}
template <bool F>
static __device__ __forceinline__ void wait_A(bool pubwave) {
  if constexpr (F) {
    // w<2 queue: A(8) oldest + out(4) newest -> vmcnt(4) retires all A, outs fly.
    if (pubwave)
      asm volatile("s_waitcnt vmcnt(4)" ::: "memory");
    else
      asm volatile("s_waitcnt vmcnt(0)" ::: "memory");
    __builtin_amdgcn_sched_barrier(0);
  }
}
template <bool B> struct BoolC { static constexpr bool value = B; };

// 256 blocks x 512 threads. Group g (16 batch rows) x col-block jb (32 cols); 8 waves
// k-split 1024 (wave w reads exactly the 4 supplier blocks jb=w*4..+3 it watches).
// Per-wave flags (2/block), single barrier/step, waves 2-7 run ahead. Triple-buffered
// hy_ex: consumer spin at step s+3 certifies all reads of buf[s%3] done (flag s+2
// posts after barrier(s+2) which follows every wave's buf[s%3] read). out[] stores
// deferred one step so no vmcnt(0) on the critical path ever waits DRAM acks.
__global__ __launch_bounds__(512, 2) void ron_kernel(
    const float* __restrict__ x, const float* __restrict__ x2h,
    const float* __restrict__ h2h, const float* __restrict__ bias,
    const float* __restrict__ gam_, const float* __restrict__ eps_,
    float* __restrict__ out, unsigned int* __restrict__ flags,
    unsigned int* __restrict__ hy_ex) {
  const int tid = threadIdx.x;
  const int w = tid >> 6;  // 0..7
  const int l = tid & 63;
  const int lc = l & 15;
  const int kg = l >> 4;

  __shared__ f32x4 part[2][8][2][64];  // 32KB, double-buffered by s&1
  __shared__ int info_sh;

  unsigned int* base = flags + 8192;  // byte 32768
  unsigned int* xcdtab = base;        // [0..255]
  unsigned int* ctr = base + 256;
  unsigned int* abortw = base + 257;
  unsigned int* enttab = base + 272;  // [0..255]

  // ---- publish my XCD (every block) ----
  if (tid == 0) {
    unsigned int myxcd = __builtin_amdgcn_s_getreg(63508) & 15u;  // hwreg(XCC_ID=20,0,32)
    __hip_atomic_store(xcdtab + blockIdx.x, 0x100u | myxcd, __ATOMIC_RELAXED,
                       __HIP_MEMORY_SCOPE_AGENT);
    __hip_atomic_fetch_add(ctr, 1u, __ATOMIC_RELAXED, __HIP_MEMORY_SCOPE_AGENT);
  }

  // ---- block 0: build the (g, jb, mode) table — single source of truth (r8-proven) ----
  if (blockIdx.x == 0 && tid == 0) {
    int gu = 0;
    while (__hip_atomic_load(ctr, __ATOMIC_RELAXED, __HIP_MEMORY_SCOPE_AGENT) < 256u) {
      if (++gu > (1 << 17)) break;
      __builtin_amdgcn_s_sleep(8);
    }
    bool ok = (gu <= (1 << 17));
    unsigned char xs[256];
    if (ok) {
      for (int i = 0; i < 256; ++i) {
        unsigned int v = __hip_atomic_load(xcdtab + i, __ATOMIC_RELAXED, __HIP_MEMORY_SCOPE_AGENT);
        int g2 = 0;
        while (v == 0 && ++g2 <= 8192) {
          __builtin_amdgcn_s_sleep(2);
          v = __hip_atomic_load(xcdtab + i, __ATOMIC_RELAXED, __HIP_MEMORY_SCOPE_AGENT);
        }
        if (v == 0) { ok = false; break; }
        xs[i] = (unsigned char)(v & 15u);
      }
    }
    unsigned int ent[256];
    if (ok) {
      int gidx = 0, nl = 0;
      unsigned char left[256], tmp[256];
      for (unsigned int xc = 0; xc < 16u && gidx < 8; ++xc) {
        int cnt = 0;
        for (int i = 0; i < 256; ++i)
          if (xs[i] == (unsigned char)xc) tmp[cnt++] = (unsigned char)i;
        int p = 0;
        while (cnt - p >= 32 && gidx < 8) {  // exact-32 co-XCD set -> fast
          for (int k2 = 0; k2 < 32; ++k2)
            ent[tmp[p + k2]] = 1u | ((unsigned)gidx << 1) | ((unsigned)k2 << 4) | (1u << 9);
          ++gidx; p += 32;
        }
        for (; p < cnt; ++p) left[nl++] = tmp[p];
      }
      int li = 0;
      while (gidx < 8) {  // mixed leftovers -> slow (agent/IC, proven)
        for (int k2 = 0; k2 < 32 && li < nl; ++k2, ++li)
          ent[left[li]] = 1u | ((unsigned)gidx << 1) | ((unsigned)k2 << 4);
        ++gidx;
      }
    } else {
      for (int i = 0; i < 256; ++i)
        ent[i] = 1u | ((unsigned)(i & 7) << 1) | ((unsigned)(i >> 3) << 4);
    }
    for (int i = 0; i < 256; ++i)
      __hip_atomic_store(enttab + i, ent[i], __ATOMIC_RELAXED, __HIP_MEMORY_SCOPE_AGENT);
  }

  // ---- every block: fetch my entry ----
  if (tid == 0) {
    unsigned int e = 0;
    int gu = 0;
    for (;;) {
      e = __hip_atomic_load(enttab + blockIdx.x, __ATOMIC_RELAXED, __HIP_MEMORY_SCOPE_AGENT);
      if (e || ++gu > (1 << 17)) break;
      __builtin_amdgcn_s_sleep(16);
    }
    if (!e) e = 1u | ((unsigned)(blockIdx.x & 7) << 1) | ((unsigned)(blockIdx.x >> 3) << 4);
    info_sh = (int)e;
  }
  __syncthreads();
  const unsigned int ent = (unsigned int)info_sh;
  const int g = (ent >> 1) & 7;
  const int jb = (ent >> 4) & 31;
  const bool fastm = ((ent >> 9) & 1) != 0;

  // ---- one-time: h2h k-slice (wave's 4 k-tiles) x 2 col-tiles, hi/lo bf16 ----
  short8 wfh[4][2], wfl[4][2];
#pragma unroll
  for (int j = 0; j < 4; ++j) {
    const int krow = (w * 4 + j) * 32 + kg * 8;
#pragma unroll
    for (int t = 0; t < 2; ++t) {
      const int c = jb * 32 + t * 16 + lc;
#pragma unroll
      for (int jj = 0; jj < 8; ++jj) {
        float v = h2h[(size_t)(krow + jj) * NH + c];
        unsigned short hb = f2bf(v);
        wfh[j][t][jj] = (short)hb;
        wfl[j][t][jj] = (short)f2bf(v - bf2f(hb));
      }
    }
  }
  const int myc = jb * 32 + w * 16 + lc;  // owned col (waves 0,1 only)
  short8 xwh[3], xwl[3];
  float bias_c = 0.f, gam = 0.f, ep = 0.f;
  if (w < 2) {
#pragma unroll
    for (int kt = 0; kt < 3; ++kt)
#pragma unroll
      for (int jj = 0; jj < 8; ++jj) {
        float v = x2h[(size_t)(kt * 32 + kg * 8 + jj) * NH + myc];
        unsigned short hb = f2bf(v);
        xwh[kt][jj] = (short)hb;
        xwl[kt][jj] = (short)f2bf(v - bf2f(hb));
      }
    bias_c = bias[myc];
    gam = gam_[myc];
    ep = eps_[myc];
  }

  float hy[4] = {0.f, 0.f, 0.f, 0.f};
  float hz[4] = {0.f, 0.f, 0.f, 0.f};
  const float* xlane = x + (size_t)(g * 16 + lc) * LSEQ * NI + kg * 8;
  const int aoff = lc * 8 + kg * 2;  // u64 units within a 128-u64 chunk
  // per-wave flags: 64 per group, 64B-spaced. myflag used by waves 0,1 only.
  unsigned int* myflag = flags + (size_t)(g * 64 + jb * 2 + w) * 16;
  unsigned int* watch =
      flags + (size_t)(g * 64 + (w * 4 + ((l >> 1) & 3)) * 2 + (l & 1)) * 16;
  const int ktc = myc >> 5, kgc = (myc >> 3) & 3, sh = myc & 7;

  // out pointers, one per accumulator row; advanced by NH each stored step
  float* op[4];
  if (w < 2) {
#pragma unroll
    for (int i = 0; i < 4; ++i)
      op[i] = out + (size_t)(g * 16 + kg * 4 + i) * LSEQ * NH + myc;
  }

  // ---- prefetch x for s=0 ----
  f32x4 xr[6];
  if (w < 2) {
#pragma unroll
    for (int kt = 0; kt < 3; ++kt) {
      xr[2 * kt] = *(const f32x4*)(xlane + kt * 32);
      xr[2 * kt + 1] = *(const f32x4*)(xlane + kt * 32 + 4);
    }
  }

  auto run = [&](auto fc) {
    constexpr bool F = decltype(fc)::value;
    bool noSync = false;  // watchdog: trip -> never wait again (fast, visible failure)
    for (int s = 0; s < LSEQ; ++s) {
      const int wb = s % 3;            // write buffer
      const int rb = wb ? wb - 1 : 2;  // read buffer = (s-1)%3

      if (s) {
        // ---- spin: 4 suppliers x 2 publishing waves. Fast: L2-endpoint atomics ----
        if (!noSync) {
          int guard = 0;
          for (;;) {
            unsigned int v;
            if constexpr (F) {
              v = 0x7FFFFFFFu;
              if (l < 8)
                v = __hip_atomic_fetch_add(watch, 0u, __ATOMIC_RELAXED,
                                           __HIP_MEMORY_SCOPE_WORKGROUP);
            } else {
              v = __hip_atomic_load(watch, __ATOMIC_RELAXED, __HIP_MEMORY_SCOPE_AGENT);
            }
            if (!__any((int)v < s)) break;
            if ((++guard & 255) == 0) {
              if (__hip_atomic_load(abortw, __ATOMIC_RELAXED, __HIP_MEMORY_SCOPE_AGENT) != 0u ||
                  guard > (1 << 16)) {
                __hip_atomic_store(abortw, 1u, __ATOMIC_RELAXED, __HIP_MEMORY_SCOPE_AGENT);
                noSync = true;
                break;
              }
            }
            __builtin_amdgcn_s_sleep(1);
          }
        }
        asm volatile("" ::: "memory");
        __builtin_amdgcn_sched_barrier(0);
      }

      // ---- pack x(s) from regs loaded last iter (queue clean here -> free wait) ----
      short8 axh[3], axl[3];
      if (w < 2) {
#pragma unroll
        for (int kt = 0; kt < 3; ++kt) {
#pragma unroll
          for (int jj = 0; jj < 4; ++jj) {
            unsigned short hb = f2bf(xr[2 * kt][jj]);
            axh[kt][jj] = (short)hb;
            axl[kt][jj] = (short)f2bf(xr[2 * kt][jj] - bf2f(hb));
            unsigned short hb2 = f2bf(xr[2 * kt + 1][jj]);
            axh[kt][jj + 4] = (short)hb2;
            axl[kt][jj + 4] = (short)f2bf(xr[2 * kt + 1][jj] - bf2f(hb2));
          }
        }
      }

      f32x4 a0a = {0.f, 0.f, 0.f, 0.f}, a0b = {0.f, 0.f, 0.f, 0.f};
      f32x4 a1a = {0.f, 0.f, 0.f, 0.f}, a1b = {0.f, 0.f, 0.f, 0.f};
      f32x4 accx = {0.f, 0.f, 0.f, 0.f};
      u64x2 hq[4], lq[4];

      if (s) {
        // ---- issue A-loads FIRST (oldest in queue) ----
        const u64* srcg = (const u64*)hy_ex + (size_t)(rb * 8 + g) * 8192;
#pragma unroll
        for (int j = 0; j < 4; ++j) {
          const int idx = (w * 4 + j) * 128 + aoff;
          ld16_issue<F>(&hq[j], srcg + idx);
          ld16_issue<F>(&lq[j], srcg + 4096 + idx);
        }
        // ---- then out[s-1] stores (hy still holds step s-1; acks ride under MFMAs) ----
        if (w < 2) {
#pragma unroll
          for (int i = 0; i < 4; ++i) {
            st_out(op[i], hy[i]);
            op[i] += NH;
          }
        }
      }

      // ---- x-projection MFMAs (waves 0,1): overlap the A-load round trip ----
      if (w < 2) {
#pragma unroll
        for (int kt = 0; kt < 3; ++kt) {
          accx = __builtin_amdgcn_mfma_f32_16x16x32_bf16(axh[kt], xwh[kt], accx, 0, 0, 0);
          accx = __builtin_amdgcn_mfma_f32_16x16x32_bf16(axl[kt], xwh[kt], accx, 0, 0, 0);
          accx = __builtin_amdgcn_mfma_f32_16x16x32_bf16(axh[kt], xwl[kt], accx, 0, 0, 0);
        }
      }

      if (s) {
        wait_A<F>(w < 2);  // fast: vmcnt(4) for pub-waves (outs fly) / vmcnt(0) others
#pragma unroll
        for (int j = 0; j < 4; ++j) {
          short8 fh = __builtin_bit_cast(short8, hq[j]);
          short8 fl = __builtin_bit_cast(short8, lq[j]);
          if (j & 1) {
            a0b = __builtin_amdgcn_mfma_f32_16x16x32_bf16(fh, wfh[j][0], a0b, 0, 0, 0);
            a1b = __builtin_amdgcn_mfma_f32_16x16x32_bf16(fh, wfh[j][1], a1b, 0, 0, 0);
            a0b = __builtin_amdgcn_mfma_f32_16x16x32_bf16(fl, wfh[j][0], a0b, 0, 0, 0);
            a1b = __builtin_amdgcn_mfma_f32_16x16x32_bf16(fl, wfh[j][1], a1b, 0, 0, 0);
            a0b = __builtin_amdgcn_mfma_f32_16x16x32_bf16(fh, wfl[j][0], a0b, 0, 0, 0);
            a1b = __builtin_amdgcn_mfma_f32_16x16x32_bf16(fh, wfl[j][1], a1b, 0, 0, 0);
          } else {
            a0a = __builtin_amdgcn_mfma_f32_16x16x32_bf16(fh, wfh[j][0], a0a, 0, 0, 0);
            a1a = __builtin_amdgcn_mfma_f32_16x16x32_bf16(fh, wfh[j][1], a1a, 0, 0, 0);
            a0a = __builtin_amdgcn_mfma_f32_16x16x32_bf16(fl, wfh[j][0], a0a, 0, 0, 0);
            a1a = __builtin_amdgcn_mfma_f32_16x16x32_bf16(fl, wfh[j][1], a1a, 0, 0, 0);
            a0a = __builtin_amdgcn_mfma_f32_16x16x32_bf16(fh, wfl[j][0], a0a, 0, 0, 0);
            a1a = __builtin_amdgcn_mfma_f32_16x16x32_bf16(fh, wfl[j][1], a1a, 0, 0, 0);
          }
        }
      }

      // ---- cross-wave k-reduction via LDS (double-buffered; ONE barrier/step) ----
      part[s & 1][w][0][l] = a0a + a0b;
      part[s & 1][w][1][l] = a1a + a1b;
      __syncthreads();
      // waves 2-7: run ahead into step s+1 (spin + A-loads + MFMAs)

      if (w < 2) {
        f32x4 r = accx;
#pragma unroll
        for (int ww = 0; ww < 8; ++ww) r += part[s & 1][ww][w][l];

        unsigned int* dstg = hy_ex + (size_t)(wb * 8 + g) * 16384;
#pragma unroll
        for (int i = 0; i < 4; ++i) {
          float a = r[i] + bias_c;
          float th = fast_tanhf(a);
          hz[i] += DT * (th - gam * hy[i] - ep * hz[i]);
          hy[i] += DT * hz[i];
          const int rr = kg * 4 + i;
          unsigned short hb = f2bf(hy[i]);
          unsigned short lb = f2bf(hy[i] - bf2f(hb));
          unsigned int oh = (unsigned int)__shfl_xor((int)hb, 1, 64);
          unsigned int ol = (unsigned int)__shfl_xor((int)lb, 1, 64);
          if (!(lc & 1)) {  // even col stores the (c, c+1) pair
            const int u32idx = (ktc * 512 + rr * 32 + kgc * 8 + sh) >> 1;
            stpub<F>(dstg + u32idx, (unsigned int)hb | (oh << 16));
            stpub<F>(dstg + 8192 + u32idx, (unsigned int)lb | (ol << 16));
          }
        }
        drain_vm();  // waits pub L2-acks only (outs retired under the MFMA phase)
        if (l == 0) stflag<F>(myflag, (unsigned int)(s + 1));

        // ---- x(s+1) prefetch: lands in queue behind the flag store, off the path ----
        const float* xs2 = xlane + (size_t)(s + 1 < LSEQ ? s + 1 : s) * NI;
#pragma unroll
        for (int kt = 0; kt < 3; ++kt) {
          xr[2 * kt] = *(const f32x4*)(xs2 + kt * 32);
          xr[2 * kt + 1] = *(const f32x4*)(xs2 + kt * 32 + 4);
        }
      }
    }
    // ---- epilogue: flush the deferred final-step outputs ----
    if (w < 2) {
#pragma unroll
      for (int i = 0; i < 4; ++i) *op[i] = hy[i];
    }
  };

  if (fastm)
    run(BoolC<true>{});
  else
    run(BoolC<false>{});
}

extern "C" void kernel_launch(void* const* d_in, const int* in_sizes, int n_in,
                              void* d_out, int out_size, void* d_ws, size_t ws_size,
                              hipStream_t stream) {
  const float* x = (const float*)d_in[0];
  const float* x2h = (const float*)d_in[1];
  const float* h2h = (const float*)d_in[2];
  const float* bias = (const float*)d_in[3];
  const float* gam = (const float*)d_in[4];
  const float* eps = (const float*)d_in[5];
  float* out = (float*)d_out;

  unsigned int* flags = (unsigned int*)d_ws;                   // 32KB per-wave flags + tables
  unsigned int* hy_ex = (unsigned int*)((char*)d_ws + 65536);  // 3 bufs x 8 groups x 64KB

  // zero flags + discovery + mapping table every call (step 0 never reads hy_ex)
  hipMemsetAsync(d_ws, 0, 65536, stream);

  ron_kernel<<<dim3(256), dim3(512), 0, stream>>>(x, x2h, h2h, bias, gam, eps, out, flags, hy_ex);
}

// Round 12
// 2195.559 us; speedup vs baseline: 4.7765x; 4.7765x over previous
//
#include <hip/hip_runtime.h>
#include <math.h>

typedef short short8 __attribute__((ext_vector_type(8)));
typedef float f32x4 __attribute__((ext_vector_type(4)));
typedef unsigned long long u64;
typedef u64 u64x2 __attribute__((ext_vector_type(2)));

#define DT 0.042f
#define LSEQ 512
#define NI 96
#define NH 1024

static __device__ __forceinline__ unsigned short f2bf(float f) {
  unsigned int u = __builtin_bit_cast(unsigned int, f);
  return (unsigned short)((u + 0x7fffu + ((u >> 16) & 1u)) >> 16);
}
static __device__ __forceinline__ float bf2f(unsigned short h) {
  unsigned int u = ((unsigned int)h) << 16;
  return __builtin_bit_cast(float, u);
}
static __device__ __forceinline__ float fast_tanhf(float a) {
  float ax = __builtin_fabsf(a);
  float e = __expf(2.0f * ax);  // overflow -> inf -> t = 1, no NaN
  float t = 1.0f - 2.0f / (e + 1.0f);
  return a < 0.0f ? -t : t;
}

// Transports (scoreboard from r2..r11):
//  - hy_ex DATA: sc0 loads/stores (XCD L2) on verified co-XCD groups [r8-proven];
//    agent relaxed atomics (IC) otherwise [r5-proven].
//  - FLAGS: posts = agent relaxed atomic store; polls = agent relaxed atomic LOAD
//    (the only poll transport that works: sc0 loads are L1-stale (r9), L2 atomic
//    RMWs collapse under contention (r11)).
template <bool F>
static __device__ __forceinline__ void ld16_issue(u64x2* dst, const u64* p) {
  if constexpr (F) {
    asm volatile("global_load_dwordx4 %0, %1, off sc0" : "=v"(*dst) : "v"(p) : "memory");
  } else {
    u64 a = __hip_atomic_load(p, __ATOMIC_RELAXED, __HIP_MEMORY_SCOPE_AGENT);
    u64 b = __hip_atomic_load(p + 1, __ATOMIC_RELAXED, __HIP_MEMORY_SCOPE_AGENT);
    *dst = (u64x2){a, b};
  }
}
template <bool F>
static __device__ __forceinline__ void stpub(unsigned int* p, unsigned int v) {
  if constexpr (F)
    asm volatile("global_store_dword %0, %1, off sc0" ::"v"(p), "v"(v) : "memory");
  else
    __hip_atomic_store(p, v, __ATOMIC_RELAXED, __HIP_MEMORY_SCOPE_AGENT);
}
static __device__ __forceinline__ void st_out(float* p, float v) {
  asm volatile("global_store_dword %0, %1, off" ::"v"(p), "v"(v) : "memory");
}
static __device__ __forceinline__ void drain_vm() {  // wave-local full drain
  asm volatile("s_waitcnt vmcnt(0)" ::: "memory");
  __builtin_amdgcn_sched_barrier(0);
}
template <bool F>
static __device__ __forceinline__ void wait_A(bool pubwave) {
  if constexpr (F) {
    // pub-wave queue after spin: A(8) oldest + out(4) newest -> vmcnt(4) retires A.
    if (pubwave)
      asm volatile("s_waitcnt vmcnt(4)" ::: "memory");
    else
      asm volatile("s_waitcnt vmcnt(0)" ::: "memory");
    __builtin_amdgcn_sched_barrier(0);
  }
}
template <bool B> struct BoolC { static constexpr bool value = B; };

// 256 blocks x 512 threads. Group g (16 batch rows) x col-block jb (32 cols); 8 waves
// k-split 1024. SINGLE-POLLER sync: only wave 0 polls the group's 64 per-wave flags
// (one per lane, agent loads); a top-of-step s_barrier releases the other 7 waves —
// poll fabric traffic cut 64x vs r10 (the theory for r8/r10's inflated step time).
// Flag posts: waves 0,1 each drain their own sc0 publish stores (vmcnt(0), wave-local)
// then post their own agent flag. Triple-buffered hy_ex: top-barrier passes only when
// all 64 flags >= s (all blocks done step s-1 => their step s-2 reads of buf[s%3]
// done) -> safe to overwrite buf[s%3] at step s. out[] stores deferred one step so
// no vmcnt wait on the critical path ever blocks on DRAM acks (r11-proven).
__global__ __launch_bounds__(512, 2) void ron_kernel(
    const float* __restrict__ x, const float* __restrict__ x2h,
    const float* __restrict__ h2h, const float* __restrict__ bias,
    const float* __restrict__ gam_, const float* __restrict__ eps_,
    float* __restrict__ out, unsigned int* __restrict__ flags,
    unsigned int* __restrict__ hy_ex) {
  const int tid = threadIdx.x;
  const int w = tid >> 6;  // 0..7
  const int l = tid & 63;
  const int lc = l & 15;
  const int kg = l >> 4;

  __shared__ f32x4 part[2][8][2][64];  // 32KB, double-buffered by s&1
  __shared__ int info_sh;

  unsigned int* base = flags + 8192;  // byte 32768
  unsigned int* xcdtab = base;        // [0..255]
  unsigned int* ctr = base + 256;
  unsigned int* abortw = base + 257;
  unsigned int* enttab = base + 272;  // [0..255]

  // ---- publish my XCD (every block) ----
  if (tid == 0) {
    unsigned int myxcd = __builtin_amdgcn_s_getreg(63508) & 15u;  // hwreg(XCC_ID=20,0,32)
    __hip_atomic_store(xcdtab + blockIdx.x, 0x100u | myxcd, __ATOMIC_RELAXED,
                       __HIP_MEMORY_SCOPE_AGENT);
    __hip_atomic_fetch_add(ctr, 1u, __ATOMIC_RELAXED, __HIP_MEMORY_SCOPE_AGENT);
  }

  // ---- block 0: build the (g, jb, mode) table — single source of truth (r8-proven) ----
  if (blockIdx.x == 0 && tid == 0) {
    int gu = 0;
    while (__hip_atomic_load(ctr, __ATOMIC_RELAXED, __HIP_MEMORY_SCOPE_AGENT) < 256u) {
      if (++gu > (1 << 17)) break;
      __builtin_amdgcn_s_sleep(8);
    }
    bool ok = (gu <= (1 << 17));
    unsigned char xs[256];
    if (ok) {
      for (int i = 0; i < 256; ++i) {
        unsigned int v = __hip_atomic_load(xcdtab + i, __ATOMIC_RELAXED, __HIP_MEMORY_SCOPE_AGENT);
        int g2 = 0;
        while (v == 0 && ++g2 <= 8192) {
          __builtin_amdgcn_s_sleep(2);
          v = __hip_atomic_load(xcdtab + i, __ATOMIC_RELAXED, __HIP_MEMORY_SCOPE_AGENT);
        }
        if (v == 0) { ok = false; break; }
        xs[i] = (unsigned char)(v & 15u);
      }
    }
    unsigned int ent[256];
    if (ok) {
      int gidx = 0, nl = 0;
      unsigned char left[256], tmp[256];
      for (unsigned int xc = 0; xc < 16u && gidx < 8; ++xc) {
        int cnt = 0;
        for (int i = 0; i < 256; ++i)
          if (xs[i] == (unsigned char)xc) tmp[cnt++] = (unsigned char)i;
        int p = 0;
        while (cnt - p >= 32 && gidx < 8) {  // exact-32 co-XCD set -> fast
          for (int k2 = 0; k2 < 32; ++k2)
            ent[tmp[p + k2]] = 1u | ((unsigned)gidx << 1) | ((unsigned)k2 << 4) | (1u << 9);
          ++gidx; p += 32;
        }
        for (; p < cnt; ++p) left[nl++] = tmp[p];
      }
      int li = 0;
      while (gidx < 8) {  // mixed leftovers -> slow (agent/IC, proven)
        for (int k2 = 0; k2 < 32 && li < nl; ++k2, ++li)
          ent[left[li]] = 1u | ((unsigned)gidx << 1) | ((unsigned)k2 << 4);
        ++gidx;
      }
    } else {
      for (int i = 0; i < 256; ++i)
        ent[i] = 1u | ((unsigned)(i & 7) << 1) | ((unsigned)(i >> 3) << 4);
    }
    for (int i = 0; i < 256; ++i)
      __hip_atomic_store(enttab + i, ent[i], __ATOMIC_RELAXED, __HIP_MEMORY_SCOPE_AGENT);
  }

  // ---- every block: fetch my entry ----
  if (tid == 0) {
    unsigned int e = 0;
    int gu = 0;
    for (;;) {
      e = __hip_atomic_load(enttab + blockIdx.x, __ATOMIC_RELAXED, __HIP_MEMORY_SCOPE_AGENT);
      if (e || ++gu > (1 << 17)) break;
      __builtin_amdgcn_s_sleep(16);
    }
    if (!e) e = 1u | ((unsigned)(blockIdx.x & 7) << 1) | ((unsigned)(blockIdx.x >> 3) << 4);
    info_sh = (int)e;
  }
  __syncthreads();
  const unsigned int ent = (unsigned int)info_sh;
  const int g = (ent >> 1) & 7;
  const int jb = (ent >> 4) & 31;
  const bool fastm = ((ent >> 9) & 1) != 0;

  // ---- one-time: h2h k-slice (wave's 4 k-tiles) x 2 col-tiles, hi/lo bf16 ----
  short8 wfh[4][2], wfl[4][2];
#pragma unroll
  for (int j = 0; j < 4; ++j) {
    const int krow = (w * 4 + j) * 32 + kg * 8;
#pragma unroll
    for (int t = 0; t < 2; ++t) {
      const int c = jb * 32 + t * 16 + lc;
#pragma unroll
      for (int jj = 0; jj < 8; ++jj) {
        float v = h2h[(size_t)(krow + jj) * NH + c];
        unsigned short hb = f2bf(v);
        wfh[j][t][jj] = (short)hb;
        wfl[j][t][jj] = (short)f2bf(v - bf2f(hb));
      }
    }
  }
  const int myc = jb * 32 + w * 16 + lc;  // owned col (waves 0,1 only)
  short8 xwh[3], xwl[3];
  float bias_c = 0.f, gam = 0.f, ep = 0.f;
  if (w < 2) {
#pragma unroll
    for (int kt = 0; kt < 3; ++kt)
#pragma unroll
      for (int jj = 0; jj < 8; ++jj) {
        float v = x2h[(size_t)(kt * 32 + kg * 8 + jj) * NH + myc];
        unsigned short hb = f2bf(v);
        xwh[kt][jj] = (short)hb;
        xwl[kt][jj] = (short)f2bf(v - bf2f(hb));
      }
    bias_c = bias[myc];
    gam = gam_[myc];
    ep = eps_[myc];
  }

  float hy[4] = {0.f, 0.f, 0.f, 0.f};
  float hz[4] = {0.f, 0.f, 0.f, 0.f};
  const float* xlane = x + (size_t)(g * 16 + lc) * LSEQ * NI + kg * 8;
  const int aoff = lc * 8 + kg * 2;  // u64 units within a 128-u64 chunk
  // per-wave flags: 64 per group, 64B-spaced. Posted by waves 0,1; polled by wave 0.
  unsigned int* myflag = flags + (size_t)(g * 64 + jb * 2 + w) * 16;
  unsigned int* watch = flags + (size_t)(g * 64 + l) * 16;  // wave 0: lane l -> flag l
  const int ktc = myc >> 5, kgc = (myc >> 3) & 3, sh = myc & 7;

  // out pointers, one per accumulator row; advanced by NH each stored step
  float* op[4];
  if (w < 2) {
#pragma unroll
    for (int i = 0; i < 4; ++i)
      op[i] = out + (size_t)(g * 16 + kg * 4 + i) * LSEQ * NH + myc;
  }

  // ---- prefetch x for s=0 ----
  f32x4 xr[6];
  if (w < 2) {
#pragma unroll
    for (int kt = 0; kt < 3; ++kt) {
      xr[2 * kt] = *(const f32x4*)(xlane + kt * 32);
      xr[2 * kt + 1] = *(const f32x4*)(xlane + kt * 32 + 4);
    }
  }

  auto run = [&](auto fc) {
    constexpr bool F = decltype(fc)::value;
    bool noSync = false;  // wave 0 only; trip -> never wait again (visible failure)
    for (int s = 0; s < LSEQ; ++s) {
      const int wb = s % 3;            // write buffer
      const int rb = wb ? wb - 1 : 2;  // read buffer = (s-1)%3

      if (s) {
        // ---- single-poller spin: wave 0, one agent-load per lane per iteration ----
        if (w == 0 && !noSync) {
          int guard = 0;
          for (;;) {
            unsigned int v =
                __hip_atomic_load(watch, __ATOMIC_RELAXED, __HIP_MEMORY_SCOPE_AGENT);
            if (!__any((int)v < s)) break;
            if ((++guard & 1023) == 0) {
              bool ab = false;
              if (l == 0)
                ab = (__hip_atomic_load(abortw, __ATOMIC_RELAXED,
                                        __HIP_MEMORY_SCOPE_AGENT) != 0u);
              if (__any(ab) || guard > (1 << 16)) {
                if (l == 0)
                  __hip_atomic_store(abortw, 1u, __ATOMIC_RELAXED, __HIP_MEMORY_SCOPE_AGENT);
                noSync = true;
                break;
              }
            }
            __builtin_amdgcn_s_sleep(1);
          }
        }
        __syncthreads();  // releases waves 1-7 (local s_barrier, zero fabric traffic)
      }

      // ---- pack x(s) from regs loaded last iter ----
      short8 axh[3], axl[3];
      if (w < 2) {
#pragma unroll
        for (int kt = 0; kt < 3; ++kt) {
#pragma unroll
          for (int jj = 0; jj < 4; ++jj) {
            unsigned short hb = f2bf(xr[2 * kt][jj]);
            axh[kt][jj] = (short)hb;
            axl[kt][jj] = (short)f2bf(xr[2 * kt][jj] - bf2f(hb));
            unsigned short hb2 = f2bf(xr[2 * kt + 1][jj]);
            axh[kt][jj + 4] = (short)hb2;
            axl[kt][jj + 4] = (short)f2bf(xr[2 * kt + 1][jj] - bf2f(hb2));
          }
        }
      }

      f32x4 a0a = {0.f, 0.f, 0.f, 0.f}, a0b = {0.f, 0.f, 0.f, 0.f};
      f32x4 a1a = {0.f, 0.f, 0.f, 0.f}, a1b = {0.f, 0.f, 0.f, 0.f};
      f32x4 accx = {0.f, 0.f, 0.f, 0.f};
      u64x2 hq[4], lq[4];

      if (s) {
        // ---- issue A-loads FIRST (oldest in queue) ----
        const u64* srcg = (const u64*)hy_ex + (size_t)(rb * 8 + g) * 8192;
#pragma unroll
        for (int j = 0; j < 4; ++j) {
          const int idx = (w * 4 + j) * 128 + aoff;
          ld16_issue<F>(&hq[j], srcg + idx);
          ld16_issue<F>(&lq[j], srcg + 4096 + idx);
        }
        // ---- then out[s-1] stores (hy holds step s-1; acks ride under MFMAs) ----
        if (w < 2) {
#pragma unroll
          for (int i = 0; i < 4; ++i) {
            st_out(op[i], hy[i]);
            op[i] += NH;
          }
        }
      }

      // ---- x-projection MFMAs (waves 0,1): overlap the A-load round trip ----
      if (w < 2) {
#pragma unroll
        for (int kt = 0; kt < 3; ++kt) {
          accx = __builtin_amdgcn_mfma_f32_16x16x32_bf16(axh[kt], xwh[kt], accx, 0, 0, 0);
          accx = __builtin_amdgcn_mfma_f32_16x16x32_bf16(axl[kt], xwh[kt], accx, 0, 0, 0);
          accx = __builtin_amdgcn_mfma_f32_16x16x32_bf16(axh[kt], xwl[kt], accx, 0, 0, 0);
        }
      }

      if (s) {
        wait_A<F>(w < 2);  // fast: vmcnt(4) pub-waves (outs fly) / vmcnt(0) others
#pragma unroll
        for (int j = 0; j < 4; ++j) {
          short8 fh = __builtin_bit_cast(short8, hq[j]);
          short8 fl = __builtin_bit_cast(short8, lq[j]);
          if (j & 1) {
            a0b = __builtin_amdgcn_mfma_f32_16x16x32_bf16(fh, wfh[j][0], a0b, 0, 0, 0);
            a1b = __builtin_amdgcn_mfma_f32_16x16x32_bf16(fh, wfh[j][1], a1b, 0, 0, 0);
            a0b = __builtin_amdgcn_mfma_f32_16x16x32_bf16(fl, wfh[j][0], a0b, 0, 0, 0);
            a1b = __builtin_amdgcn_mfma_f32_16x16x32_bf16(fl, wfh[j][1], a1b, 0, 0, 0);
            a0b = __builtin_amdgcn_mfma_f32_16x16x32_bf16(fh, wfl[j][0], a0b, 0, 0, 0);
            a1b = __builtin_amdgcn_mfma_f32_16x16x32_bf16(fh, wfl[j][1], a1b, 0, 0, 0);
          } else {
            a0a = __builtin_amdgcn_mfma_f32_16x16x32_bf16(fh, wfh[j][0], a0a, 0, 0, 0);
            a1a = __builtin_amdgcn_mfma_f32_16x16x32_bf16(fh, wfh[j][1], a1a, 0, 0, 0);
            a0a = __builtin_amdgcn_mfma_f32_16x16x32_bf16(fl, wfh[j][0], a0a, 0, 0, 0);
            a1a = __builtin_amdgcn_mfma_f32_16x16x32_bf16(fl, wfh[j][1], a1a, 0, 0, 0);
            a0a = __builtin_amdgcn_mfma_f32_16x16x32_bf16(fh, wfl[j][0], a0a, 0, 0, 0);
            a1a = __builtin_amdgcn_mfma_f32_16x16x32_bf16(fh, wfl[j][1], a1a, 0, 0, 0);
          }
        }
      }

      // ---- cross-wave k-reduction via LDS ----
      part[s & 1][w][0][l] = a0a + a0b;
      part[s & 1][w][1][l] = a1a + a1b;
      __syncthreads();

      if (w < 2) {
        f32x4 r = accx;
#pragma unroll
        for (int ww = 0; ww < 8; ++ww) r += part[s & 1][ww][w][l];

        unsigned int* dstg = hy_ex + (size_t)(wb * 8 + g) * 16384;
#pragma unroll
        for (int i = 0; i < 4; ++i) {
          float a = r[i] + bias_c;
          float th = fast_tanhf(a);
          hz[i] += DT * (th - gam * hy[i] - ep * hz[i]);
          hy[i] += DT * hz[i];
          const int rr = kg * 4 + i;
          unsigned short hb = f2bf(hy[i]);
          unsigned short lb = f2bf(hy[i] - bf2f(hb));
          unsigned int oh = (unsigned int)__shfl_xor((int)hb, 1, 64);
          unsigned int ol = (unsigned int)__shfl_xor((int)lb, 1, 64);
          if (!(lc & 1)) {  // even col stores the (c, c+1) pair
            const int u32idx = (ktc * 512 + rr * 32 + kgc * 8 + sh) >> 1;
            stpub<F>(dstg + u32idx, (unsigned int)hb | (oh << 16));
            stpub<F>(dstg + 8192 + u32idx, (unsigned int)lb | (ol << 16));
          }
        }
        drain_vm();  // wave-local: publishes L2-acked (outs retired under MFMAs)
        if (l == 0)
          __hip_atomic_store(myflag, (unsigned int)(s + 1), __ATOMIC_RELAXED,
                             __HIP_MEMORY_SCOPE_AGENT);

        // ---- x(s+1) prefetch: behind the flag post, off the critical path ----
        const float* xs2 = xlane + (size_t)(s + 1 < LSEQ ? s + 1 : s) * NI;
#pragma unroll
        for (int kt = 0; kt < 3; ++kt) {
          xr[2 * kt] = *(const f32x4*)(xs2 + kt * 32);
          xr[2 * kt + 1] = *(const f32x4*)(xs2 + kt * 32 + 4);
        }
      }
    }
    // ---- epilogue: flush the deferred final-step outputs ----
    if (w < 2) {
#pragma unroll
      for (int i = 0; i < 4; ++i) *op[i] = hy[i];
    }
  };

  if (fastm)
    run(BoolC<true>{});
  else
    run(BoolC<false>{});
}

extern "C" void kernel_launch(void* const* d_in, const int* in_sizes, int n_in,
                              void* d_out, int out_size, void* d_ws, size_t ws_size,
                              hipStream_t stream) {
  const float* x = (const float*)d_in[0];
  const float* x2h = (const float*)d_in[1];
  const float* h2h = (const float*)d_in[2];
  const float* bias = (const float*)d_in[3];
  const float* gam = (const float*)d_in[4];
  const float* eps = (const float*)d_in[5];
  float* out = (float*)d_out;

  unsigned int* flags = (unsigned int*)d_ws;                   // 32KB per-wave flags + tables
  unsigned int* hy_ex = (unsigned int*)((char*)d_ws + 65536);  // 3 bufs x 8 groups x 64KB

  // zero flags + discovery + mapping table every call (step 0 never reads hy_ex)
  hipMemsetAsync(d_ws, 0, 65536, stream);

  ron_kernel<<<dim3(256), dim3(512), 0, stream>>>(x, x2h, h2h, bias, gam, eps, out, flags, hy_ex);
}